// Round 1
// baseline (1485.299 us; speedup 1.0000x reference)
//
#include <hip/hip_runtime.h>
#include <hip/hip_bf16.h>

#define C 128           // channels (C_IN == C_HID == 128)
#define GEMM_BM 64      // rows per GEMM block

// ---------------- GEMM: out[n][j] = sum_k in[n][k] * W[j][k]  (in @ W^T) ----
// block 256 threads: 16x16 thread grid, each thread computes 4 rows x 8 cols.
__global__ __launch_bounds__(256) void k_gemm(
    const float* __restrict__ in, const float* __restrict__ W,
    float* __restrict__ out_raw, float* __restrict__ out_relu, int n)
{
    __shared__ float Wt[C][C + 4];     // Wt[k][j] = W[j][k], padded
    __shared__ float it[GEMM_BM][33];  // input k-chunk staging, padded

    const int t = threadIdx.x;
    // stage W transposed
    for (int i = t; i < C * C; i += 256) {
        int j = i >> 7, k = i & 127;
        Wt[k][j] = W[i];
    }

    const int row0 = blockIdx.x * GEMM_BM;
    const int tx = t & 15;   // col group: cols tx*8 .. tx*8+7
    const int ty = t >> 4;   // row group: rows ty*4 .. ty*4+3

    float acc[4][8];
    #pragma unroll
    for (int i = 0; i < 4; ++i)
        #pragma unroll
        for (int j = 0; j < 8; ++j) acc[i][j] = 0.f;

    for (int kc = 0; kc < C; kc += 32) {
        __syncthreads();   // Wt ready (first iter) / previous it consumed
        for (int i = t; i < GEMM_BM * 32; i += 256) {
            int r = i >> 5, k = i & 31;
            int gr = row0 + r;
            it[r][k] = (gr < n) ? in[(size_t)gr * C + kc + k] : 0.f;
        }
        __syncthreads();
        #pragma unroll
        for (int k = 0; k < 32; ++k) {
            float m0 = it[ty * 4 + 0][k];
            float m1 = it[ty * 4 + 1][k];
            float m2 = it[ty * 4 + 2][k];
            float m3 = it[ty * 4 + 3][k];
            const float* wr = &Wt[kc + k][tx * 8];
            #pragma unroll
            for (int j = 0; j < 8; ++j) {
                float w = wr[j];
                acc[0][j] = fmaf(m0, w, acc[0][j]);
                acc[1][j] = fmaf(m1, w, acc[1][j]);
                acc[2][j] = fmaf(m2, w, acc[2][j]);
                acc[3][j] = fmaf(m3, w, acc[3][j]);
            }
        }
    }

    #pragma unroll
    for (int i = 0; i < 4; ++i) {
        int gr = row0 + ty * 4 + i;
        if (gr < n) {
            float* orow = out_raw + (size_t)gr * C + tx * 8;
            if (out_relu) {
                float* rrow = out_relu + (size_t)gr * C + tx * 8;
                #pragma unroll
                for (int j = 0; j < 8; ++j) {
                    float v = acc[i][j];
                    orow[j] = v;
                    rrow[j] = fmaxf(v, 0.f);
                }
            } else {
                #pragma unroll
                for (int j = 0; j < 8; ++j) orow[j] = acc[i][j];
            }
        }
    }
}

// ---------------- degree count ----------------
__global__ void k_deg(const int* __restrict__ src, const int* __restrict__ dst,
                      int* __restrict__ deg, int nE, int nN)
{
    int e = blockIdx.x * 256 + threadIdx.x;
    if (e >= nE) return;
    atomicAdd(&deg[dst[e]], 1);        // in-degree of dst
    atomicAdd(&deg[nN + src[e]], 1);   // out-degree of src
}

// ---------------- exclusive scan (3 kernels, chunk 512) ----------------
__global__ void k_scan1(const int* __restrict__ deg, int* __restrict__ off,
                        int* __restrict__ part, int n2)
{
    __shared__ int s[512];
    int t = threadIdx.x;
    int idx = blockIdx.x * 512 + t;
    int v = (idx < n2) ? deg[idx] : 0;
    s[t] = v;
    for (int o = 1; o < 512; o <<= 1) {
        __syncthreads();
        int x = (t >= o) ? s[t - o] : 0;
        __syncthreads();
        s[t] += x;
    }
    if (idx < n2) off[idx] = s[t] - v;        // exclusive
    if (t == 511) part[blockIdx.x] = s[511];  // block total
}

__global__ void k_scan2(int* __restrict__ part, int nb)
{
    __shared__ int s[512];
    int t = threadIdx.x;
    int v = (t < nb) ? part[t] : 0;
    s[t] = v;
    for (int o = 1; o < 512; o <<= 1) {
        __syncthreads();
        int x = (t >= o) ? s[t - o] : 0;
        __syncthreads();
        s[t] += x;
    }
    if (t < nb) part[t] = s[t] - v;           // exclusive, in place
}

__global__ void k_scan3(int* __restrict__ off, const int* __restrict__ part, int n2)
{
    int idx = blockIdx.x * 256 + threadIdx.x;
    if (idx < n2) off[idx] += part[idx >> 9];
}

// ---------------- CSR fill ----------------
__global__ void k_fill(const int* __restrict__ src, const int* __restrict__ dst,
                       const int* __restrict__ off, int* __restrict__ cnt,
                       int* __restrict__ csr, int nE, int nN)
{
    int e = blockIdx.x * 256 + threadIdx.x;
    if (e >= nE) return;
    int s = src[e], d = dst[e];
    csr[off[d] + atomicAdd(&cnt[d], 1)] = s;            // in-neighbors of d
    csr[off[nN + s] + atomicAdd(&cnt[nN + s], 1)] = d;  // out-neighbors of s
}

// ---------------- aggregation: mu = relu(x_emb + gather(t2,in) + gather(t3,out))
// one 64-lane group per node, 2 channels (float2) per lane
__global__ __launch_bounds__(256) void k_agg(
    const float* __restrict__ t2, const float* __restrict__ t3,
    const float* __restrict__ x_emb, float* __restrict__ mu_out,
    const int* __restrict__ csr, const int* __restrict__ off,
    const int* __restrict__ deg, int nN)
{
    int g = blockIdx.x * 4 + (threadIdx.x >> 6);   // node index
    int lane = threadIdx.x & 63;
    if (g >= nN) return;

    float2 acc = *(const float2*)&x_emb[(size_t)g * C + lane * 2];

    int o = off[g], e = o + deg[g];
    for (int i = o; i < e; ++i) {
        int u = csr[i];
        float2 v = *(const float2*)&t2[(size_t)u * C + lane * 2];
        acc.x += v.x; acc.y += v.y;
    }
    o = off[nN + g]; e = o + deg[nN + g];
    for (int i = o; i < e; ++i) {
        int w = csr[i];
        float2 v = *(const float2*)&t3[(size_t)w * C + lane * 2];
        acc.x += v.x; acc.y += v.y;
    }
    float2 r;
    r.x = fmaxf(acc.x, 0.f);
    r.y = fmaxf(acc.y, 0.f);
    *(float2*)&mu_out[(size_t)g * C + lane * 2] = r;
}

// ---------------- final reduction: out[c] = sum_n mu[n][c] ----------------
__global__ void k_reduce(const float* __restrict__ mu, float* __restrict__ out, int nN)
{
    int c = threadIdx.x;   // 128 threads = 128 channels
    float acc = 0.f;
    for (int r = blockIdx.x; r < nN; r += gridDim.x)
        acc += mu[(size_t)r * C + c];
    atomicAdd(&out[c], acc);
}

extern "C" void kernel_launch(void* const* d_in, const int* in_sizes, int n_in,
                              void* d_out, int out_size, void* d_ws, size_t ws_size,
                              hipStream_t stream)
{
    const float* x  = (const float*)d_in[0];
    const int*   ei = (const int*)d_in[1];
    const float* W1 = (const float*)d_in[2];
    const float* W2 = (const float*)d_in[3];
    const float* W3 = (const float*)d_in[4];
    float* out = (float*)d_out;

    const int nN = in_sizes[0] / C;
    const int nE = in_sizes[1] / 2;
    const int* src = ei;
    const int* dst = ei + nE;

    const size_t SZ = (size_t)nN * C * sizeof(float);
    char* p = (char*)d_ws;
    auto alloc = [&](size_t bytes) {
        char* r = p;
        p += (bytes + 511) & ~(size_t)511;
        return r;
    };
    float* x_emb = (float*)alloc(SZ);
    float* mu    = (float*)alloc(SZ);
    float* t2    = (float*)alloc(SZ);
    float* t3    = (float*)alloc(SZ);
    int* deg  = (int*)alloc((size_t)2 * nN * 4);
    int* off  = (int*)alloc((size_t)2 * nN * 4);
    int* cnt  = (int*)alloc((size_t)2 * nN * 4);
    int* part = (int*)alloc(512 * 4);
    int* csr  = (int*)alloc((size_t)2 * nE * 4);

    hipMemsetAsync(deg, 0, (size_t)2 * nN * 4, stream);
    hipMemsetAsync(cnt, 0, (size_t)2 * nN * 4, stream);
    hipMemsetAsync(out, 0, (size_t)out_size * 4, stream);

    const int gemm_grid = (nN + GEMM_BM - 1) / GEMM_BM;

    // x_emb = x @ W1^T ; mu = relu(x_emb)   (iteration 1 has zero messages)
    k_gemm<<<gemm_grid, 256, 0, stream>>>(x, W1, x_emb, mu, nN);

    // build CSR (in-lists at off[0..nN), out-lists at off[nN..2nN))
    k_deg<<<(nE + 255) / 256, 256, 0, stream>>>(src, dst, deg, nE, nN);
    const int n2 = 2 * nN;
    const int nb = (n2 + 511) / 512;
    k_scan1<<<nb, 512, 0, stream>>>(deg, off, part, n2);
    k_scan2<<<1, 512, 0, stream>>>(part, nb);
    k_scan3<<<(n2 + 255) / 256, 256, 0, stream>>>(off, part, n2);
    k_fill<<<(nE + 255) / 256, 256, 0, stream>>>(src, dst, off, cnt, csr, nE, nN);

    // iterations 2 and 3
    for (int it = 0; it < 2; ++it) {
        k_gemm<<<gemm_grid, 256, 0, stream>>>(mu, W2, t2, nullptr, nN);
        k_gemm<<<gemm_grid, 256, 0, stream>>>(mu, W3, t3, nullptr, nN);
        k_agg<<<(nN + 3) / 4, 256, 0, stream>>>(t2, t3, x_emb, mu, csr, off, deg, nN);
    }

    k_reduce<<<512, 128, 0, stream>>>(mu, out, nN);
}

// Round 2
// 1044.960 us; speedup vs baseline: 1.4214x; 1.4214x over previous
//
#include <hip/hip_runtime.h>
#include <hip/hip_bf16.h>

#define C 128

typedef __attribute__((ext_vector_type(8))) short bf16x8;
typedef __attribute__((ext_vector_type(4))) float f32x4;

__device__ __forceinline__ unsigned short f2bf(float f) {
    unsigned u = __builtin_bit_cast(unsigned, f);
    u += 0x7fff + ((u >> 16) & 1);          // RNE
    return (unsigned short)(u >> 16);
}
__device__ __forceinline__ float bflo(unsigned v) {
    return __builtin_bit_cast(float, v << 16);
}
__device__ __forceinline__ float bfhi(unsigned v) {
    return __builtin_bit_cast(float, v & 0xffff0000u);
}

// ---------------- k_emb: x_emb = x @ W1^T (bf16 out), mu = relu(x_emb) ------
// 512 threads = 8 waves, each wave does 16 rows x 128 cols via MFMA.
__global__ __launch_bounds__(512) void k_emb(
    const float* __restrict__ x, const float* __restrict__ W1,
    unsigned short* __restrict__ x_emb, unsigned short* __restrict__ mu, int nN)
{
    __shared__ unsigned short Wl[C * C];   // bf16, XOR-swizzled 16B chunks
    const int t = threadIdx.x;
    for (int i = t; i < C * C / 8; i += 512) {   // 2048 chunks of 8 elems
        int j = i >> 4, c = i & 15;
        const float* src = W1 + j * C + c * 8;
        float4 f0 = *(const float4*)src;
        float4 f1 = *(const float4*)(src + 4);
        alignas(16) unsigned short tmp[8] = {
            f2bf(f0.x), f2bf(f0.y), f2bf(f0.z), f2bf(f0.w),
            f2bf(f1.x), f2bf(f1.y), f2bf(f1.z), f2bf(f1.w)};
        int cs = c ^ (j & 7);
        *(uint4*)&Wl[j * C + cs * 8] = *(const uint4*)tmp;
    }
    __syncthreads();

    const int lane = t & 63, w = t >> 6;
    const int r0 = blockIdx.x * 128 + w * 16;
    if (r0 >= nN) return;
    const int lj = lane & 15, lk = lane >> 4;
    const int arow = r0 + lj;      // nN % 16 == 0 -> always valid

    bf16x8 a[4];
    #pragma unroll
    for (int ks = 0; ks < 4; ++ks) {
        const float* ap = x + (size_t)arow * C + ks * 32 + lk * 8;
        float4 f0 = *(const float4*)ap;
        float4 f1 = *(const float4*)(ap + 4);
        alignas(16) unsigned short tmp[8] = {
            f2bf(f0.x), f2bf(f0.y), f2bf(f0.z), f2bf(f0.w),
            f2bf(f1.x), f2bf(f1.y), f2bf(f1.z), f2bf(f1.w)};
        a[ks] = *(const bf16x8*)tmp;
    }

    #pragma unroll
    for (int ct = 0; ct < 8; ++ct) {
        int j = ct * 16 + lj;
        f32x4 acc = {0.f, 0.f, 0.f, 0.f};
        #pragma unroll
        for (int ks = 0; ks < 4; ++ks) {
            int slot = (ks * 4 + lk) ^ (j & 7);
            bf16x8 b = *(const bf16x8*)&Wl[j * C + slot * 8];
            acc = __builtin_amdgcn_mfma_f32_16x16x32_bf16(a[ks], b, acc, 0, 0, 0);
        }
        #pragma unroll
        for (int r = 0; r < 4; ++r) {
            int row = r0 + lk * 4 + r;
            float v = acc[r];
            x_emb[(size_t)row * C + j] = f2bf(v);
            mu[(size_t)row * C + j]    = f2bf(fmaxf(v, 0.f));
        }
    }
}

// ---------------- k_mm2: t2 = mu @ W2^T, t3 = mu @ W3^T  (bf16 in/out) ------
__global__ __launch_bounds__(512) void k_mm2(
    const unsigned short* __restrict__ mu, const float* __restrict__ W2,
    const float* __restrict__ W3, unsigned short* __restrict__ t2,
    unsigned short* __restrict__ t3, int nN)
{
    __shared__ unsigned short Wl[2 * C * C];   // W2 then W3, swizzled
    const int t = threadIdx.x;
    for (int i = t; i < 2 * C * C / 8; i += 512) {
        int wsel = i >> 11, r = i & 2047;
        int j = r >> 4, c = r & 15;
        const float* src = (wsel ? W3 : W2) + j * C + c * 8;
        float4 f0 = *(const float4*)src;
        float4 f1 = *(const float4*)(src + 4);
        alignas(16) unsigned short tmp[8] = {
            f2bf(f0.x), f2bf(f0.y), f2bf(f0.z), f2bf(f0.w),
            f2bf(f1.x), f2bf(f1.y), f2bf(f1.z), f2bf(f1.w)};
        int cs = c ^ (j & 7);
        *(uint4*)&Wl[wsel * C * C + j * C + cs * 8] = *(const uint4*)tmp;
    }
    __syncthreads();

    const int lane = t & 63, w = t >> 6;
    const int r0 = blockIdx.x * 128 + w * 16;
    if (r0 >= nN) return;
    const int lj = lane & 15, lk = lane >> 4;
    const int arow = r0 + lj;

    bf16x8 a[4];
    #pragma unroll
    for (int ks = 0; ks < 4; ++ks)
        a[ks] = *(const bf16x8*)&mu[(size_t)arow * C + ks * 32 + lk * 8];

    #pragma unroll
    for (int ct = 0; ct < 8; ++ct) {
        int j = ct * 16 + lj;
        f32x4 acc2 = {0.f, 0.f, 0.f, 0.f};
        f32x4 acc3 = {0.f, 0.f, 0.f, 0.f};
        #pragma unroll
        for (int ks = 0; ks < 4; ++ks) {
            int slot = (ks * 4 + lk) ^ (j & 7);
            bf16x8 b2 = *(const bf16x8*)&Wl[j * C + slot * 8];
            bf16x8 b3 = *(const bf16x8*)&Wl[C * C + j * C + slot * 8];
            acc2 = __builtin_amdgcn_mfma_f32_16x16x32_bf16(a[ks], b2, acc2, 0, 0, 0);
            acc3 = __builtin_amdgcn_mfma_f32_16x16x32_bf16(a[ks], b3, acc3, 0, 0, 0);
        }
        #pragma unroll
        for (int r = 0; r < 4; ++r) {
            int row = r0 + lk * 4 + r;
            t2[(size_t)row * C + j] = f2bf(acc2[r]);
            t3[(size_t)row * C + j] = f2bf(acc3[r]);
        }
    }
}

// ---------------- degree count ----------------
__global__ void k_deg(const int* __restrict__ src, const int* __restrict__ dst,
                      int* __restrict__ deg, int nE, int nN)
{
    int e = blockIdx.x * 256 + threadIdx.x;
    if (e >= nE) return;
    atomicAdd(&deg[dst[e]], 1);
    atomicAdd(&deg[nN + src[e]], 1);
}

// ---------------- exclusive scan (3 kernels, chunk 512) ----------------
__global__ void k_scan1(const int* __restrict__ deg, int* __restrict__ off,
                        int* __restrict__ part, int n2)
{
    __shared__ int s[512];
    int t = threadIdx.x;
    int idx = blockIdx.x * 512 + t;
    int v = (idx < n2) ? deg[idx] : 0;
    s[t] = v;
    for (int o = 1; o < 512; o <<= 1) {
        __syncthreads();
        int x = (t >= o) ? s[t - o] : 0;
        __syncthreads();
        s[t] += x;
    }
    if (idx < n2) off[idx] = s[t] - v;
    if (t == 511) part[blockIdx.x] = s[511];
}

__global__ void k_scan2(int* __restrict__ part, int nb)
{
    __shared__ int s[512];
    int t = threadIdx.x;
    int v = (t < nb) ? part[t] : 0;
    s[t] = v;
    for (int o = 1; o < 512; o <<= 1) {
        __syncthreads();
        int x = (t >= o) ? s[t - o] : 0;
        __syncthreads();
        s[t] += x;
    }
    if (t < nb) part[t] = s[t] - v;
}

__global__ void k_scan3(int* __restrict__ off, const int* __restrict__ part, int n2)
{
    int idx = blockIdx.x * 256 + threadIdx.x;
    if (idx < n2) off[idx] += part[idx >> 9];
}

// ---------------- CSR fill ----------------
__global__ void k_fill(const int* __restrict__ src, const int* __restrict__ dst,
                       const int* __restrict__ off, int* __restrict__ cnt,
                       int* __restrict__ csr, int nE, int nN)
{
    int e = blockIdx.x * 256 + threadIdx.x;
    if (e >= nE) return;
    int s = src[e], d = dst[e];
    csr[off[d] + atomicAdd(&cnt[d], 1)] = s;
    csr[off[nN + s] + atomicAdd(&cnt[nN + s], 1)] = d;
}

// ---------------- aggregation (bf16 gathers) --------------------------------
// mu = relu(x_emb + gather(t2, in) + gather(t3, out)); FINAL: accumulate h_G.
template<int FINAL>
__global__ __launch_bounds__(256) void k_agg(
    const unsigned short* __restrict__ t2, const unsigned short* __restrict__ t3,
    const unsigned short* __restrict__ x_emb, unsigned short* __restrict__ mu_out,
    float* __restrict__ out,
    const int* __restrict__ csr, const int* __restrict__ off,
    const int* __restrict__ deg, int nN)
{
    const int lane = threadIdx.x & 63, w = threadIdx.x >> 6;
    float sx = 0.f, sy = 0.f;
    for (int g = blockIdx.x * 4 + w; g < nN; g += gridDim.x * 4) {
        unsigned base = *(const unsigned*)&x_emb[(size_t)g * C + lane * 2];
        float ax = bflo(base), ay = bfhi(base);
        int o = off[g], e = o + deg[g];
        for (int i = o; i < e; ++i) {
            int u = csr[i];
            unsigned v = *(const unsigned*)&t2[(size_t)u * C + lane * 2];
            ax += bflo(v); ay += bfhi(v);
        }
        o = off[nN + g]; e = o + deg[nN + g];
        for (int i = o; i < e; ++i) {
            int u = csr[i];
            unsigned v = *(const unsigned*)&t3[(size_t)u * C + lane * 2];
            ax += bflo(v); ay += bfhi(v);
        }
        float rx = fmaxf(ax, 0.f), ry = fmaxf(ay, 0.f);
        if (FINAL) {
            sx += rx; sy += ry;
        } else {
            unsigned pk = ((unsigned)f2bf(ry) << 16) | (unsigned)f2bf(rx);
            *(unsigned*)&mu_out[(size_t)g * C + lane * 2] = pk;
        }
    }
    if (FINAL) {
        __shared__ float red[512];
        red[threadIdx.x * 2]     = sx;
        red[threadIdx.x * 2 + 1] = sy;
        __syncthreads();
        if (w == 0) {
            float ax = red[lane * 2]       + red[(64 + lane) * 2] +
                       red[(128 + lane) * 2] + red[(192 + lane) * 2];
            float ay = red[lane * 2 + 1]       + red[(64 + lane) * 2 + 1] +
                       red[(128 + lane) * 2 + 1] + red[(192 + lane) * 2 + 1];
            atomicAdd(&out[lane * 2], ax);
            atomicAdd(&out[lane * 2 + 1], ay);
        }
    }
}

extern "C" void kernel_launch(void* const* d_in, const int* in_sizes, int n_in,
                              void* d_out, int out_size, void* d_ws, size_t ws_size,
                              hipStream_t stream)
{
    const float* x  = (const float*)d_in[0];
    const int*   ei = (const int*)d_in[1];
    const float* W1 = (const float*)d_in[2];
    const float* W2 = (const float*)d_in[3];
    const float* W3 = (const float*)d_in[4];
    float* out = (float*)d_out;

    const int nN = in_sizes[0] / C;
    const int nE = in_sizes[1] / 2;
    const int* src = ei;
    const int* dst = ei + nE;

    const size_t SZH = (size_t)nN * C * 2;   // bf16 node array
    char* p = (char*)d_ws;
    auto alloc = [&](size_t bytes) {
        char* r = p;
        p += (bytes + 511) & ~(size_t)511;
        return r;
    };
    unsigned short* x_emb = (unsigned short*)alloc(SZH);
    unsigned short* mu    = (unsigned short*)alloc(SZH);
    unsigned short* t2    = (unsigned short*)alloc(SZH);
    unsigned short* t3    = (unsigned short*)alloc(SZH);
    int* deg  = (int*)alloc((size_t)2 * nN * 4);
    int* off  = (int*)alloc((size_t)2 * nN * 4);
    int* cnt  = (int*)alloc((size_t)2 * nN * 4);
    int* part = (int*)alloc(512 * 4);
    int* csr  = (int*)alloc((size_t)2 * nE * 4);

    hipMemsetAsync(deg, 0, (size_t)2 * nN * 4, stream);
    hipMemsetAsync(cnt, 0, (size_t)2 * nN * 4, stream);
    hipMemsetAsync(out, 0, (size_t)out_size * 4, stream);

    const int mm_grid = (nN + 127) / 128;

    // iteration 1: mu = relu(x @ W1^T)
    k_emb<<<mm_grid, 512, 0, stream>>>(x, W1, x_emb, mu, nN);

    // CSR build
    k_deg<<<(nE + 255) / 256, 256, 0, stream>>>(src, dst, deg, nE, nN);
    const int n2 = 2 * nN;
    const int nb = (n2 + 511) / 512;
    k_scan1<<<nb, 512, 0, stream>>>(deg, off, part, n2);
    k_scan2<<<1, 512, 0, stream>>>(part, nb);
    k_scan3<<<(n2 + 255) / 256, 256, 0, stream>>>(off, part, n2);
    k_fill<<<(nE + 255) / 256, 256, 0, stream>>>(src, dst, off, cnt, csr, nE, nN);

    // iteration 2
    k_mm2<<<mm_grid, 512, 0, stream>>>(mu, W2, W3, t2, t3, nN);
    k_agg<0><<<(nN + 3) / 4, 256, 0, stream>>>(t2, t3, x_emb, mu, out, csr, off, deg, nN);
    // iteration 3 (fused final reduce; mu never materialized)
    k_mm2<<<mm_grid, 512, 0, stream>>>(mu, W2, W3, t2, t3, nN);
    k_agg<1><<<2048, 256, 0, stream>>>(t2, t3, x_emb, nullptr, out, csr, off, deg, nN);
}

// Round 3
// 752.227 us; speedup vs baseline: 1.9745x; 1.3892x over previous
//
#include <hip/hip_runtime.h>
#include <hip/hip_bf16.h>

#define C 128

typedef __attribute__((ext_vector_type(8))) short bf16x8;
typedef __attribute__((ext_vector_type(4))) float f32x4;

__device__ __forceinline__ unsigned short f2bf(float f) {
    unsigned u = __builtin_bit_cast(unsigned, f);
    u += 0x7fff + ((u >> 16) & 1);          // RNE
    return (unsigned short)(u >> 16);
}
__device__ __forceinline__ float bflo(unsigned v) {
    return __builtin_bit_cast(float, v << 16);
}
__device__ __forceinline__ float bfhi(unsigned v) {
    return __builtin_bit_cast(float, v & 0xffff0000u);
}

// ---------------- k_emb: x_emb = x @ W1^T (bf16 out), mu = relu(x_emb) ------
__global__ __launch_bounds__(512) void k_emb(
    const float* __restrict__ x, const float* __restrict__ W1,
    unsigned short* __restrict__ x_emb, unsigned short* __restrict__ mu, int nN)
{
    __shared__ unsigned short Wl[C * C];   // bf16, XOR-swizzled 16B chunks
    const int t = threadIdx.x;
    for (int i = t; i < C * C / 8; i += 512) {
        int j = i >> 4, c = i & 15;
        const float* src = W1 + j * C + c * 8;
        float4 f0 = *(const float4*)src;
        float4 f1 = *(const float4*)(src + 4);
        alignas(16) unsigned short tmp[8] = {
            f2bf(f0.x), f2bf(f0.y), f2bf(f0.z), f2bf(f0.w),
            f2bf(f1.x), f2bf(f1.y), f2bf(f1.z), f2bf(f1.w)};
        int cs = c ^ (j & 7);
        *(uint4*)&Wl[j * C + cs * 8] = *(const uint4*)tmp;
    }
    __syncthreads();

    const int lane = t & 63, w = t >> 6;
    const int r0 = blockIdx.x * 128 + w * 16;
    if (r0 >= nN) return;
    const int lj = lane & 15, lk = lane >> 4;
    const int arow = r0 + lj;

    bf16x8 a[4];
    #pragma unroll
    for (int ks = 0; ks < 4; ++ks) {
        const float* ap = x + (size_t)arow * C + ks * 32 + lk * 8;
        float4 f0 = *(const float4*)ap;
        float4 f1 = *(const float4*)(ap + 4);
        alignas(16) unsigned short tmp[8] = {
            f2bf(f0.x), f2bf(f0.y), f2bf(f0.z), f2bf(f0.w),
            f2bf(f1.x), f2bf(f1.y), f2bf(f1.z), f2bf(f1.w)};
        a[ks] = *(const bf16x8*)tmp;
    }

    #pragma unroll
    for (int ct = 0; ct < 8; ++ct) {
        int j = ct * 16 + lj;
        f32x4 acc = {0.f, 0.f, 0.f, 0.f};
        #pragma unroll
        for (int ks = 0; ks < 4; ++ks) {
            int slot = (ks * 4 + lk) ^ (j & 7);
            bf16x8 b = *(const bf16x8*)&Wl[j * C + slot * 8];
            acc = __builtin_amdgcn_mfma_f32_16x16x32_bf16(a[ks], b, acc, 0, 0, 0);
        }
        #pragma unroll
        for (int r = 0; r < 4; ++r) {
            int row = r0 + lk * 4 + r;
            float v = acc[r];
            x_emb[(size_t)row * C + j] = f2bf(v);
            mu[(size_t)row * C + j]    = f2bf(fmaxf(v, 0.f));
        }
    }
}

// ---------------- k_mm2: t2 = mu @ W2^T, t3 = mu @ W3^T  (bf16 in/out) ------
__global__ __launch_bounds__(512) void k_mm2(
    const unsigned short* __restrict__ mu, const float* __restrict__ W2,
    const float* __restrict__ W3, unsigned short* __restrict__ t2,
    unsigned short* __restrict__ t3, int nN)
{
    __shared__ unsigned short Wl[2 * C * C];   // W2 then W3, swizzled
    const int t = threadIdx.x;
    for (int i = t; i < 2 * C * C / 8; i += 512) {
        int wsel = i >> 11, r = i & 2047;
        int j = r >> 4, c = r & 15;
        const float* src = (wsel ? W3 : W2) + j * C + c * 8;
        float4 f0 = *(const float4*)src;
        float4 f1 = *(const float4*)(src + 4);
        alignas(16) unsigned short tmp[8] = {
            f2bf(f0.x), f2bf(f0.y), f2bf(f0.z), f2bf(f0.w),
            f2bf(f1.x), f2bf(f1.y), f2bf(f1.z), f2bf(f1.w)};
        int cs = c ^ (j & 7);
        *(uint4*)&Wl[wsel * C * C + j * C + cs * 8] = *(const uint4*)tmp;
    }
    __syncthreads();

    const int lane = t & 63, w = t >> 6;
    const int r0 = blockIdx.x * 128 + w * 16;
    if (r0 >= nN) return;
    const int lj = lane & 15, lk = lane >> 4;
    const int arow = r0 + lj;

    bf16x8 a[4];
    #pragma unroll
    for (int ks = 0; ks < 4; ++ks)
        a[ks] = *(const bf16x8*)&mu[(size_t)arow * C + ks * 32 + lk * 8];

    #pragma unroll
    for (int ct = 0; ct < 8; ++ct) {
        int j = ct * 16 + lj;
        f32x4 acc2 = {0.f, 0.f, 0.f, 0.f};
        f32x4 acc3 = {0.f, 0.f, 0.f, 0.f};
        #pragma unroll
        for (int ks = 0; ks < 4; ++ks) {
            int slot = (ks * 4 + lk) ^ (j & 7);
            bf16x8 b2 = *(const bf16x8*)&Wl[j * C + slot * 8];
            bf16x8 b3 = *(const bf16x8*)&Wl[C * C + j * C + slot * 8];
            acc2 = __builtin_amdgcn_mfma_f32_16x16x32_bf16(a[ks], b2, acc2, 0, 0, 0);
            acc3 = __builtin_amdgcn_mfma_f32_16x16x32_bf16(a[ks], b3, acc3, 0, 0, 0);
        }
        #pragma unroll
        for (int r = 0; r < 4; ++r) {
            int row = r0 + lk * 4 + r;
            t2[(size_t)row * C + j] = f2bf(acc2[r]);
            t3[(size_t)row * C + j] = f2bf(acc3[r]);
        }
    }
}

// ---------------- degree count ----------------
__global__ void k_deg(const int* __restrict__ src, const int* __restrict__ dst,
                      int* __restrict__ deg, int nE, int nN)
{
    int e = blockIdx.x * 256 + threadIdx.x;
    if (e >= nE) return;
    atomicAdd(&deg[dst[e]], 1);
    atomicAdd(&deg[nN + src[e]], 1);
}

// ---------------- exclusive scan (3 kernels, chunk 512) ----------------
__global__ void k_scan1(const int* __restrict__ deg, int* __restrict__ off,
                        int* __restrict__ part, int n2)
{
    __shared__ int s[512];
    int t = threadIdx.x;
    int idx = blockIdx.x * 512 + t;
    int v = (idx < n2) ? deg[idx] : 0;
    s[t] = v;
    for (int o = 1; o < 512; o <<= 1) {
        __syncthreads();
        int x = (t >= o) ? s[t - o] : 0;
        __syncthreads();
        s[t] += x;
    }
    if (idx < n2) off[idx] = s[t] - v;
    if (t == 511) part[blockIdx.x] = s[511];
}

__global__ void k_scan2(int* __restrict__ part, int nb)
{
    __shared__ int s[512];
    int t = threadIdx.x;
    int v = (t < nb) ? part[t] : 0;
    s[t] = v;
    for (int o = 1; o < 512; o <<= 1) {
        __syncthreads();
        int x = (t >= o) ? s[t - o] : 0;
        __syncthreads();
        s[t] += x;
    }
    if (t < nb) part[t] = s[t] - v;
}

__global__ void k_scan3(int* __restrict__ off, const int* __restrict__ part, int n2)
{
    int idx = blockIdx.x * 256 + threadIdx.x;
    if (idx < n2) off[idx] += part[idx >> 9];
}

// ---------------- CSR fill ----------------
__global__ void k_fill(const int* __restrict__ src, const int* __restrict__ dst,
                       const int* __restrict__ off, int* __restrict__ cnt,
                       int* __restrict__ csr, int nE, int nN)
{
    int e = blockIdx.x * 256 + threadIdx.x;
    if (e >= nE) return;
    int s = src[e], d = dst[e];
    csr[off[d] + atomicAdd(&cnt[d], 1)] = s;
    csr[off[nN + s] + atomicAdd(&cnt[nN + s], 1)] = d;
}

// ---------------- aggregation (bf16 gathers, 4x unrolled for MLP) ----------
template<int FINAL>
__global__ __launch_bounds__(256) void k_agg(
    const unsigned short* __restrict__ t2, const unsigned short* __restrict__ t3,
    const unsigned short* __restrict__ x_emb, unsigned short* __restrict__ mu_out,
    float* __restrict__ out,
    const int* __restrict__ csr, const int* __restrict__ off,
    const int* __restrict__ deg, int nN)
{
    const int lane = threadIdx.x & 63, w = threadIdx.x >> 6;
    const int lo = lane * 2;
    float sx = 0.f, sy = 0.f;
    for (int g = blockIdx.x * 4 + w; g < nN; g += gridDim.x * 4) {
        unsigned base = *(const unsigned*)&x_emb[(size_t)g * C + lo];
        float ax = bflo(base), ay = bfhi(base);
        float bx = 0.f, by = 0.f;

        // in-neighbors -> t2
        {
            int o = off[g], e = o + deg[g], i = o;
            for (; i + 4 <= e; i += 4) {
                int u0 = csr[i + 0], u1 = csr[i + 1];
                int u2 = csr[i + 2], u3 = csr[i + 3];
                unsigned v0 = *(const unsigned*)&t2[(size_t)u0 * C + lo];
                unsigned v1 = *(const unsigned*)&t2[(size_t)u1 * C + lo];
                unsigned v2 = *(const unsigned*)&t2[(size_t)u2 * C + lo];
                unsigned v3 = *(const unsigned*)&t2[(size_t)u3 * C + lo];
                ax += bflo(v0); ay += bfhi(v0);
                bx += bflo(v1); by += bfhi(v1);
                ax += bflo(v2); ay += bfhi(v2);
                bx += bflo(v3); by += bfhi(v3);
            }
            for (; i < e; ++i) {
                int u = csr[i];
                unsigned v = *(const unsigned*)&t2[(size_t)u * C + lo];
                ax += bflo(v); ay += bfhi(v);
            }
        }
        // out-neighbors -> t3
        {
            int o = off[nN + g], e = o + deg[nN + g], i = o;
            for (; i + 4 <= e; i += 4) {
                int u0 = csr[i + 0], u1 = csr[i + 1];
                int u2 = csr[i + 2], u3 = csr[i + 3];
                unsigned v0 = *(const unsigned*)&t3[(size_t)u0 * C + lo];
                unsigned v1 = *(const unsigned*)&t3[(size_t)u1 * C + lo];
                unsigned v2 = *(const unsigned*)&t3[(size_t)u2 * C + lo];
                unsigned v3 = *(const unsigned*)&t3[(size_t)u3 * C + lo];
                ax += bflo(v0); ay += bfhi(v0);
                bx += bflo(v1); by += bfhi(v1);
                ax += bflo(v2); ay += bfhi(v2);
                bx += bflo(v3); by += bfhi(v3);
            }
            for (; i < e; ++i) {
                int u = csr[i];
                unsigned v = *(const unsigned*)&t3[(size_t)u * C + lo];
                ax += bflo(v); ay += bfhi(v);
            }
        }

        float rx = fmaxf(ax + bx, 0.f), ry = fmaxf(ay + by, 0.f);
        if (FINAL) {
            sx += rx; sy += ry;
        } else {
            unsigned pk = ((unsigned)f2bf(ry) << 16) | (unsigned)f2bf(rx);
            *(unsigned*)&mu_out[(size_t)g * C + lo] = pk;
        }
    }
    if (FINAL) {
        __shared__ float red[512];
        red[threadIdx.x * 2]     = sx;
        red[threadIdx.x * 2 + 1] = sy;
        __syncthreads();
        if (w == 0) {
            float ax = red[lane * 2]         + red[(64 + lane) * 2] +
                       red[(128 + lane) * 2] + red[(192 + lane) * 2];
            float ay = red[lane * 2 + 1]         + red[(64 + lane) * 2 + 1] +
                       red[(128 + lane) * 2 + 1] + red[(192 + lane) * 2 + 1];
            atomicAdd(&out[lane * 2], ax);
            atomicAdd(&out[lane * 2 + 1], ay);
        }
    }
}

extern "C" void kernel_launch(void* const* d_in, const int* in_sizes, int n_in,
                              void* d_out, int out_size, void* d_ws, size_t ws_size,
                              hipStream_t stream)
{
    const float* x  = (const float*)d_in[0];
    const int*   ei = (const int*)d_in[1];
    const float* W1 = (const float*)d_in[2];
    const float* W2 = (const float*)d_in[3];
    const float* W3 = (const float*)d_in[4];
    float* out = (float*)d_out;

    const int nN = in_sizes[0] / C;
    const int nE = in_sizes[1] / 2;
    const int* src = ei;
    const int* dst = ei + nE;

    const size_t SZH = (size_t)nN * C * 2;   // bf16 node array
    char* p = (char*)d_ws;
    auto alloc = [&](size_t bytes) {
        char* r = p;
        p += (bytes + 511) & ~(size_t)511;
        return r;
    };
    unsigned short* x_emb = (unsigned short*)alloc(SZH);
    unsigned short* mu    = (unsigned short*)alloc(SZH);
    unsigned short* t2    = (unsigned short*)alloc(SZH);
    unsigned short* t3    = (unsigned short*)alloc(SZH);
    int* deg  = (int*)alloc((size_t)2 * nN * 4);
    int* off  = (int*)alloc((size_t)2 * nN * 4);
    int* cnt  = (int*)alloc((size_t)2 * nN * 4);
    int* part = (int*)alloc(512 * 4);
    int* csr  = (int*)alloc((size_t)2 * nE * 4);

    hipMemsetAsync(deg, 0, (size_t)2 * nN * 4, stream);
    hipMemsetAsync(cnt, 0, (size_t)2 * nN * 4, stream);
    hipMemsetAsync(out, 0, (size_t)out_size * 4, stream);

    const int mm_grid = (nN + 127) / 128;

    // iteration 1: mu = relu(x @ W1^T)
    k_emb<<<mm_grid, 512, 0, stream>>>(x, W1, x_emb, mu, nN);

    // CSR build
    k_deg<<<(nE + 255) / 256, 256, 0, stream>>>(src, dst, deg, nE, nN);
    const int n2 = 2 * nN;
    const int nb = (n2 + 511) / 512;
    k_scan1<<<nb, 512, 0, stream>>>(deg, off, part, n2);
    k_scan2<<<1, 512, 0, stream>>>(part, nb);
    k_scan3<<<(n2 + 255) / 256, 256, 0, stream>>>(off, part, n2);
    k_fill<<<(nE + 255) / 256, 256, 0, stream>>>(src, dst, off, cnt, csr, nE, nN);

    // iteration 2
    k_mm2<<<mm_grid, 512, 0, stream>>>(mu, W2, W3, t2, t3, nN);
    k_agg<0><<<(nN + 3) / 4, 256, 0, stream>>>(t2, t3, x_emb, mu, out, csr, off, deg, nN);
    // iteration 3 (fused final reduce; mu never materialized)
    k_mm2<<<mm_grid, 512, 0, stream>>>(mu, W2, W3, t2, t3, nN);
    k_agg<1><<<2048, 256, 0, stream>>>(t2, t3, x_emb, nullptr, out, csr, off, deg, nN);
}